// Round 1
// 785.113 us; speedup vs baseline: 1.0421x; 1.0421x over previous
//
#include <hip/hip_runtime.h>
#include <cstddef>

#define TT 1024
#define BB 16384
#define LC 32
#define CC (TT / LC)

typedef float v2f __attribute__((ext_vector_type(2)));

// Exact tanh via the hardware exp2: tanh(x) = 1 - 2/(2^(2*log2e*x) + 1).
// v_exp_f32 + v_rcp_f32 are ~1 ulp; saturation falls out of inf/0 handling
// (x -> +inf: rcp(inf)=0 -> 1; x -> -inf: exp2 -> 0 -> 1-2 = -1).
__device__ __forceinline__ float fast_tanh(float x) {
    float e = exp2f(x * 2.8853900817779268f);   // 2*log2(e)
    return fmaf(-2.0f, __builtin_amdgcn_rcpf(e + 1.0f), 1.0f);
}

// Phase 1: per (chunk c, batch b) run the affine recurrence from zero state,
// store the chunk offset v[c][i][b]  (layout [C][6][B] for coalescing).
__global__ __launch_bounds__(256) void k_phase1(
    const float* __restrict__ targets,
    const float* __restrict__ Wx,
    const float* __restrict__ Wu,
    float* __restrict__ v)
{
    const int b = blockIdx.x * 256 + threadIdx.x;
    const int c = blockIdx.y;
    float wx[6][6], wu[6];
#pragma unroll
    for (int i = 0; i < 6; ++i) {
        wu[i] = Wu[i];
#pragma unroll
        for (int j = 0; j < 6; ++j) wx[i][j] = Wx[i * 6 + j];
    }
    float db[6] = {0.f, 0.f, 0.f, 0.f, 0.f, 0.f};
    const int t0 = c * LC;
#pragma unroll 4
    for (int s = 0; s < LC; ++s) {
        const int t = t0 + s;
        float u = 0.0f;
        if (t > 0) u = targets[(size_t)(t - 1) * BB + b];
        float nd[6];
#pragma unroll
        for (int i = 0; i < 6; ++i) {
            float a = u * wu[i];
#pragma unroll
            for (int j = 0; j < 6; ++j) a = fmaf(db[j], wx[i][j], a);
            nd[i] = a;
        }
#pragma unroll
        for (int i = 0; i < 6; ++i) db[i] = nd[i];
    }
#pragma unroll
    for (int i = 0; i < 6; ++i) v[((size_t)c * 6 + i) * BB + b] = db[i];
}

// Phase 2: per batch b, sequential prefix over the 32 chunks.
// db_start[c+1] = db_start[c] * M + v[c],  M = (Wx^T)^32 (5 squarings).
// In-place: v[c][.][b] is replaced by db_start[c][.][b].
__global__ __launch_bounds__(256) void k_phase2(
    const float* __restrict__ Wx,
    float* __restrict__ v)
{
    const int b = blockIdx.x * 256 + threadIdx.x;
    float M[6][6];
#pragma unroll
    for (int i = 0; i < 6; ++i)
#pragma unroll
        for (int j = 0; j < 6; ++j)
            M[j][i] = Wx[i * 6 + j];  // N = Wx^T in row-vector convention
    for (int it = 0; it < 5; ++it) {
        float P[6][6];
#pragma unroll
        for (int i = 0; i < 6; ++i)
#pragma unroll
            for (int j = 0; j < 6; ++j) {
                float a = 0.0f;
#pragma unroll
                for (int k = 0; k < 6; ++k) a = fmaf(M[i][k], M[k][j], a);
                P[i][j] = a;
            }
#pragma unroll
        for (int i = 0; i < 6; ++i)
#pragma unroll
            for (int j = 0; j < 6; ++j) M[i][j] = P[i][j];
    }
    float db[6] = {0.f, 0.f, 0.f, 0.f, 0.f, 0.f};
    for (int c = 0; c < CC; ++c) {
        float vv[6];
#pragma unroll
        for (int i = 0; i < 6; ++i) {
            const size_t idx = ((size_t)c * 6 + i) * BB + b;
            vv[i] = v[idx];
            v[idx] = db[i];  // overwrite with the start state for chunk c
        }
        float nd[6];
#pragma unroll
        for (int i = 0; i < 6; ++i) {
            float a = vv[i];
#pragma unroll
            for (int j = 0; j < 6; ++j) a = fmaf(db[j], M[j][i], a);
            nd[i] = a;
        }
#pragma unroll
        for (int i = 0; i < 6; ++i) db[i] = nd[i];
    }
}

// Phase 3 v3: FOUR lanes share one (c,b) column; each lane owns 5 of the 20
// hidden units. Per-lane W1 slice = 60 floats -> total live state ~115 VGPRs,
// fits the 128-VGPR budget at 4 waves/EU (no AGPR/scratch spill traffic,
// which was the v2 bottleneck: 120 weights vs 92 architectural VGPRs).
// Units (m0,m0+1) and (m0+2,m0+3) are packed as v2f -> v_pk_fma_f32.
__global__ __launch_bounds__(256, 4) void k_phase3(
    const float* __restrict__ inputs,
    const float* __restrict__ targets,
    const float* __restrict__ Wxg,
    const float* __restrict__ Wug,
    const float* __restrict__ W1g,
    const float* __restrict__ b1g,
    const float* __restrict__ W2g,
    const float* __restrict__ b2g,
    const float* __restrict__ dbs,
    float* __restrict__ out)
{
    const int tid = threadIdx.x;
    const int q   = tid & 3;                    // which 5-unit slice
    const int b   = blockIdx.x * 64 + (tid >> 2);
    const int c   = blockIdx.y;
    const int m0  = q * 5;

    // Wave-uniform recurrence weights -> scalar loads into SGPRs.
    float wx[6][6], wu[6];
#pragma unroll
    for (int i = 0; i < 6; ++i) {
        wu[i] = Wug[i];
#pragma unroll
        for (int j = 0; j < 6; ++j) wx[i][j] = Wxg[i * 6 + j];
    }
    const float vb2 = b2g[0];

    // Per-lane W1 slice: units m0..m0+4. 60 floats total.
    v2f w01[12], w23[12];
    float w4[12];
#pragma unroll
    for (int j = 0; j < 12; ++j) {
        w01[j] = (v2f){W1g[(m0 + 0) * 12 + j], W1g[(m0 + 1) * 12 + j]};
        w23[j] = (v2f){W1g[(m0 + 2) * 12 + j], W1g[(m0 + 3) * 12 + j]};
        w4[j]  = W1g[(m0 + 4) * 12 + j];
    }
    const v2f b01 = (v2f){b1g[m0 + 0], b1g[m0 + 1]};
    const v2f b23 = (v2f){b1g[m0 + 2], b1g[m0 + 3]};
    const float b4 = b1g[m0 + 4];
    const v2f wo01 = (v2f){W2g[m0 + 0], W2g[m0 + 1]};
    const v2f wo23 = (v2f){W2g[m0 + 2], W2g[m0 + 3]};
    const float wo4 = W2g[m0 + 4];

    float db[6];
#pragma unroll
    for (int i = 0; i < 6; ++i) db[i] = dbs[((size_t)c * 6 + i) * BB + b];

    const int t0 = c * LC;
    const float* xptr = inputs + ((size_t)t0 * BB + b) * 6;
    const float* tptr = targets + (size_t)t0 * BB + b;   // = u for step t0+1
    float* optr = out + (size_t)t0 * BB + b;

    float u_cur = (t0 == 0) ? 0.0f : tptr[-(ptrdiff_t)BB];
    v2f x0 = *(const v2f*)(xptr);
    v2f x1 = *(const v2f*)(xptr + 2);
    v2f x2 = *(const v2f*)(xptr + 4);

    for (int s = 0; s < LC; ++s) {
        // Prefetch next step (addresses independent of the recurrence).
        float u_nxt = 0.0f;
        v2f n0 = x0, n1 = x1, n2 = x2;
        if (s + 1 < LC) {
            u_nxt = *tptr;
            const float* xn = xptr + (size_t)BB * 6;
            n0 = *(const v2f*)(xn);
            n1 = *(const v2f*)(xn + 2);
            n2 = *(const v2f*)(xn + 4);
        }

        // Delay-buffer update (duplicated across the 4 lanes of the column;
        // wx/wu come from SGPRs so this is 42 VALU FMAs).
        float nd[6];
#pragma unroll
        for (int i = 0; i < 6; ++i) {
            float a = u_cur * wu[i];
#pragma unroll
            for (int j = 0; j < 6; ++j) a = fmaf(db[j], wx[i][j], a);
            nd[i] = a;
        }
#pragma unroll
        for (int i = 0; i < 6; ++i) db[i] = nd[i];

        const float ni[12] = {db[0], db[1], db[2], db[3], db[4], db[5],
                              x0.x, x0.y, x1.x, x1.y, x2.x, x2.y};

        // Layer 1 for my 5 units: 2 packed pairs + 1 scalar per j.
        v2f a01 = b01, a23 = b23;
        float a4 = b4;
#pragma unroll
        for (int j = 0; j < 12; ++j) {
            const v2f nj = (v2f){ni[j], ni[j]};
            a01 = __builtin_elementwise_fma(w01[j], nj, a01);
            a23 = __builtin_elementwise_fma(w23[j], nj, a23);
            a4  = fmaf(w4[j], ni[j], a4);
        }

        // tanh + partial output over my 5 units.
        float t0u = fast_tanh(a01.x);
        float t1u = fast_tanh(a01.y);
        float t2u = fast_tanh(a23.x);
        float t3u = fast_tanh(a23.y);
        float t4u = fast_tanh(a4);
        float o = wo01.x * t0u;
        o = fmaf(wo01.y, t1u, o);
        o = fmaf(wo23.x, t2u, o);
        o = fmaf(wo23.y, t3u, o);
        o = fmaf(wo4,    t4u, o);

        // Reduce across the 4 lanes of the column.
        o += __shfl_xor(o, 1, 64);
        o += __shfl_xor(o, 2, 64);
        if (q == 0) *optr = o + vb2;

        u_cur = u_nxt; x0 = n0; x1 = n1; x2 = n2;
        xptr += (size_t)BB * 6;
        tptr += BB;
        optr += BB;
    }
}

extern "C" void kernel_launch(void* const* d_in, const int* in_sizes, int n_in,
                              void* d_out, int out_size, void* d_ws, size_t ws_size,
                              hipStream_t stream) {
    (void)in_sizes; (void)n_in; (void)out_size; (void)ws_size;
    const float* inputs  = (const float*)d_in[0];
    const float* targets = (const float*)d_in[1];
    const float* Wx = (const float*)d_in[2];
    const float* Wu = (const float*)d_in[3];
    const float* W1 = (const float*)d_in[4];
    const float* b1 = (const float*)d_in[5];
    const float* W2 = (const float*)d_in[6];
    const float* b2 = (const float*)d_in[7];
    float* out = (float*)d_out;
    float* v   = (float*)d_ws;  // needs CC*6*BB*4 = 12.6 MB of workspace

    dim3 blk(256);
    dim3 g1(BB / 256, CC);
    hipLaunchKernelGGL(k_phase1, g1, blk, 0, stream, targets, Wx, Wu, v);
    hipLaunchKernelGGL(k_phase2, dim3(BB / 256), blk, 0, stream, Wx, v);
    dim3 g3(BB / 64, CC);
    hipLaunchKernelGGL(k_phase3, g3, blk, 0, stream,
                       inputs, targets, Wx, Wu, W1, b1, W2, b2, v, out);
}

// Round 2
// 775.375 us; speedup vs baseline: 1.0552x; 1.0126x over previous
//
#include <hip/hip_runtime.h>
#include <cstddef>

#define TT 1024
#define BB 16384
#define LC 32
#define CC (TT / LC)

// Exact tanh via the hardware exp2: tanh(x) = 1 - 2/(2^(2*log2e*x) + 1).
// v_exp_f32 + v_rcp_f32; saturation falls out of inf/0 handling.
__device__ __forceinline__ float fast_tanh(float x) {
    float e = __builtin_amdgcn_exp2f(x * 2.8853900817779268f);   // 2*log2(e)
    return fmaf(-2.0f, __builtin_amdgcn_rcpf(e + 1.0f), 1.0f);
}

// Phase 1: per (chunk c, batch b) run the affine recurrence from zero state,
// store the chunk offset v[c][i][b]  (layout [C][6][B] for coalescing).
__global__ __launch_bounds__(256) void k_phase1(
    const float* __restrict__ targets,
    const float* __restrict__ Wx,
    const float* __restrict__ Wu,
    float* __restrict__ v)
{
    const int b = blockIdx.x * 256 + threadIdx.x;
    const int c = blockIdx.y;
    float wx[6][6], wu[6];
#pragma unroll
    for (int i = 0; i < 6; ++i) {
        wu[i] = Wu[i];
#pragma unroll
        for (int j = 0; j < 6; ++j) wx[i][j] = Wx[i * 6 + j];
    }
    float db[6] = {0.f, 0.f, 0.f, 0.f, 0.f, 0.f};
    const int t0 = c * LC;
#pragma unroll 4
    for (int s = 0; s < LC; ++s) {
        const int t = t0 + s;
        float u = 0.0f;
        if (t > 0) u = targets[(size_t)(t - 1) * BB + b];
        float nd[6];
#pragma unroll
        for (int i = 0; i < 6; ++i) {
            float a = u * wu[i];
#pragma unroll
            for (int j = 0; j < 6; ++j) a = fmaf(db[j], wx[i][j], a);
            nd[i] = a;
        }
#pragma unroll
        for (int i = 0; i < 6; ++i) db[i] = nd[i];
    }
#pragma unroll
    for (int i = 0; i < 6; ++i) v[((size_t)c * 6 + i) * BB + b] = db[i];
}

// Phase 2: per batch b, sequential prefix over the 32 chunks.
// db_start[c+1] = db_start[c] * M + v[c],  M = (Wx^T)^32 (5 squarings).
// In-place: v[c][.][b] is replaced by db_start[c][.][b].
__global__ __launch_bounds__(256) void k_phase2(
    const float* __restrict__ Wx,
    float* __restrict__ v)
{
    const int b = blockIdx.x * 256 + threadIdx.x;
    float M[6][6];
#pragma unroll
    for (int i = 0; i < 6; ++i)
#pragma unroll
        for (int j = 0; j < 6; ++j)
            M[j][i] = Wx[i * 6 + j];  // N = Wx^T in row-vector convention
    for (int it = 0; it < 5; ++it) {
        float P[6][6];
#pragma unroll
        for (int i = 0; i < 6; ++i)
#pragma unroll
            for (int j = 0; j < 6; ++j) {
                float a = 0.0f;
#pragma unroll
                for (int k = 0; k < 6; ++k) a = fmaf(M[i][k], M[k][j], a);
                P[i][j] = a;
            }
#pragma unroll
        for (int i = 0; i < 6; ++i)
#pragma unroll
            for (int j = 0; j < 6; ++j) M[i][j] = P[i][j];
    }
    float db[6] = {0.f, 0.f, 0.f, 0.f, 0.f, 0.f};
    for (int c = 0; c < CC; ++c) {
        float vv[6];
#pragma unroll
        for (int i = 0; i < 6; ++i) {
            const size_t idx = ((size_t)c * 6 + i) * BB + b;
            vv[i] = v[idx];
            v[idx] = db[i];  // overwrite with the start state for chunk c
        }
        float nd[6];
#pragma unroll
        for (int i = 0; i < 6; ++i) {
            float a = vv[i];
#pragma unroll
            for (int j = 0; j < 6; ++j) a = fmaf(db[j], M[j][i], a);
            nd[i] = a;
        }
#pragma unroll
        for (int i = 0; i < 6; ++i) db[i] = nd[i];
    }
}

// Phase 3 v4: four lanes per (c,b) column, 5 hidden units each — but with
// allocator-friendly PLAIN SCALAR weights (no float2/ext_vector arrays).
// v3's float2 arrays (pair-aligned operands for v_pk_fma) pushed the
// allocator into a 52-VGPR + ~76-AGPR split with per-use accvgpr copies
// (~2x issue bloat). Scalar scalars SROA cleanly; live state ~110 VGPR.
// __launch_bounds__(256,3) gives a 170-VGPR ceiling so the allocator never
// needs AGPRs; actual use ~110-120 still yields 4 waves/SIMD in HW.
__global__ __launch_bounds__(256, 3) void k_phase3(
    const float* __restrict__ inputs,
    const float* __restrict__ targets,
    const float* __restrict__ Wxg,
    const float* __restrict__ Wug,
    const float* __restrict__ W1g,
    const float* __restrict__ b1g,
    const float* __restrict__ W2g,
    const float* __restrict__ b2g,
    const float* __restrict__ dbs,
    float* __restrict__ out)
{
    const int tid = threadIdx.x;
    const int q   = tid & 3;                    // which 5-unit slice
    const int b   = blockIdx.x * 64 + (tid >> 2);
    const int c   = blockIdx.y;
    const int m0  = q * 5;

    // Wave-uniform recurrence weights -> scalar loads into SGPRs.
    float wx[6][6], wu[6];
#pragma unroll
    for (int i = 0; i < 6; ++i) {
        wu[i] = Wug[i];
#pragma unroll
        for (int j = 0; j < 6; ++j) wx[i][j] = Wxg[i * 6 + j];
    }
    const float vb2 = b2g[0];

    // Per-lane W1 slice: units m0..m0+4, 60 plain scalars.
    float w1l[5][12];
    float b1l[5], w2l[5];
#pragma unroll
    for (int p = 0; p < 5; ++p) {
#pragma unroll
        for (int j = 0; j < 12; ++j) w1l[p][j] = W1g[(m0 + p) * 12 + j];
        b1l[p] = b1g[m0 + p];
        w2l[p] = W2g[m0 + p];
    }

    float db[6];
#pragma unroll
    for (int i = 0; i < 6; ++i) db[i] = dbs[((size_t)c * 6 + i) * BB + b];

    const int t0 = c * LC;
    const float* xptr = inputs + ((size_t)t0 * BB + b) * 6;
    const float* tptr = targets + (size_t)t0 * BB + b;   // = u for step t0+1
    float* optr = out + (size_t)t0 * BB + b;

    // Inputs row is 24B (8B-aligned) -> 3x dwordx2 loads.
    float u_cur = (t0 == 0) ? 0.0f : tptr[-(ptrdiff_t)BB];
    float2 x0 = *(const float2*)(xptr);
    float2 x1 = *(const float2*)(xptr + 2);
    float2 x2 = *(const float2*)(xptr + 4);

    for (int s = 0; s < LC; ++s) {
        // Prefetch next step (addresses independent of the recurrence).
        float u_nxt = 0.0f;
        float2 n0 = x0, n1 = x1, n2 = x2;
        if (s + 1 < LC) {
            u_nxt = *tptr;
            const float* xn = xptr + (size_t)BB * 6;
            n0 = *(const float2*)(xn);
            n1 = *(const float2*)(xn + 2);
            n2 = *(const float2*)(xn + 4);
        }

        // Delay-buffer update (42 FMAs; wx/wu read from SGPRs).
        float nd[6];
#pragma unroll
        for (int i = 0; i < 6; ++i) {
            float a = u_cur * wu[i];
#pragma unroll
            for (int j = 0; j < 6; ++j) a = fmaf(db[j], wx[i][j], a);
            nd[i] = a;
        }
#pragma unroll
        for (int i = 0; i < 6; ++i) db[i] = nd[i];

        const float ni[12] = {db[0], db[1], db[2], db[3], db[4], db[5],
                              x0.x, x0.y, x1.x, x1.y, x2.x, x2.y};

        // Layer 1 for my 5 units: 60 plain scalar FMAs.
        float acc[5];
#pragma unroll
        for (int p = 0; p < 5; ++p) acc[p] = b1l[p];
#pragma unroll
        for (int j = 0; j < 12; ++j) {
            const float nij = ni[j];
#pragma unroll
            for (int p = 0; p < 5; ++p) acc[p] = fmaf(w1l[p][j], nij, acc[p]);
        }

        // tanh + partial output over my 5 units.
        float o = 0.0f;
#pragma unroll
        for (int p = 0; p < 5; ++p) o = fmaf(w2l[p], fast_tanh(acc[p]), o);

        // Reduce across the 4 lanes of the column.
        o += __shfl_xor(o, 1, 64);
        o += __shfl_xor(o, 2, 64);
        if (q == 0) *optr = o + vb2;

        u_cur = u_nxt; x0 = n0; x1 = n1; x2 = n2;
        xptr += (size_t)BB * 6;
        tptr += BB;
        optr += BB;
    }
}

extern "C" void kernel_launch(void* const* d_in, const int* in_sizes, int n_in,
                              void* d_out, int out_size, void* d_ws, size_t ws_size,
                              hipStream_t stream) {
    (void)in_sizes; (void)n_in; (void)out_size; (void)ws_size;
    const float* inputs  = (const float*)d_in[0];
    const float* targets = (const float*)d_in[1];
    const float* Wx = (const float*)d_in[2];
    const float* Wu = (const float*)d_in[3];
    const float* W1 = (const float*)d_in[4];
    const float* b1 = (const float*)d_in[5];
    const float* W2 = (const float*)d_in[6];
    const float* b2 = (const float*)d_in[7];
    float* out = (float*)d_out;
    float* v   = (float*)d_ws;  // needs CC*6*BB*4 = 12.6 MB of workspace

    dim3 blk(256);
    dim3 g1(BB / 256, CC);
    hipLaunchKernelGGL(k_phase1, g1, blk, 0, stream, targets, Wx, Wu, v);
    hipLaunchKernelGGL(k_phase2, dim3(BB / 256), blk, 0, stream, Wx, v);
    dim3 g3(BB / 64, CC);
    hipLaunchKernelGGL(k_phase3, g3, blk, 0, stream,
                       inputs, targets, Wx, Wu, W1, b1, W2, b2, v, out);
}

// Round 4
// 729.226 us; speedup vs baseline: 1.1219x; 1.0633x over previous
//
#include <hip/hip_runtime.h>
#include <cstddef>
#include <cstdint>

#define TT 1024
#define BB 16384
#define LC 32
#define CC (TT / LC)

// NOTE: __builtin_amdgcn_cvt_pkrtz returns __fp16 ext_vector_type(2) —
// _Float16 is a distinct type and does not implicitly convert (round-3 fix).
typedef __fp16 h2 __attribute__((ext_vector_type(2)));

// Exact tanh via the hardware exp2: tanh(x) = 1 - 2/(2^(2*log2e*x) + 1).
__device__ __forceinline__ float fast_tanh(float x) {
    float e = __builtin_amdgcn_exp2f(x * 2.8853900817779268f);   // 2*log2(e)
    return fmaf(-2.0f, __builtin_amdgcn_rcpf(e + 1.0f), 1.0f);
}

// ---------------------------------------------------------------------------
// Phase 1: per (chunk c, batch b) run the affine recurrence from zero state,
// store the chunk offset v[c][i][b]  (layout [C][6][B] for coalescing).
__global__ __launch_bounds__(256) void k_phase1(
    const float* __restrict__ targets,
    const float* __restrict__ Wx,
    const float* __restrict__ Wu,
    float* __restrict__ v)
{
    const int b = blockIdx.x * 256 + threadIdx.x;
    const int c = blockIdx.y;
    float wx[6][6], wu[6];
#pragma unroll
    for (int i = 0; i < 6; ++i) {
        wu[i] = Wu[i];
#pragma unroll
        for (int j = 0; j < 6; ++j) wx[i][j] = Wx[i * 6 + j];
    }
    float db[6] = {0.f, 0.f, 0.f, 0.f, 0.f, 0.f};
    const int t0 = c * LC;
#pragma unroll 4
    for (int s = 0; s < LC; ++s) {
        const int t = t0 + s;
        float u = 0.0f;
        if (t > 0) u = targets[(size_t)(t - 1) * BB + b];
        float nd[6];
#pragma unroll
        for (int i = 0; i < 6; ++i) {
            float a = u * wu[i];
#pragma unroll
            for (int j = 0; j < 6; ++j) a = fmaf(db[j], wx[i][j], a);
            nd[i] = a;
        }
#pragma unroll
        for (int i = 0; i < 6; ++i) db[i] = nd[i];
    }
#pragma unroll
    for (int i = 0; i < 6; ++i) v[((size_t)c * 6 + i) * BB + b] = db[i];
}

// ---------------------------------------------------------------------------
// Phase 2: per batch b, sequential prefix over the 32 chunks.
// db_start[c+1] = db_start[c] * M + v[c],  M = (Wx^T)^32 (5 squarings).
// In-place: v[c][.][b] is replaced by db_start[c][.][b].
__global__ __launch_bounds__(256) void k_phase2(
    const float* __restrict__ Wx,
    float* __restrict__ v)
{
    const int b = blockIdx.x * 256 + threadIdx.x;
    float M[6][6];
#pragma unroll
    for (int i = 0; i < 6; ++i)
#pragma unroll
        for (int j = 0; j < 6; ++j)
            M[j][i] = Wx[i * 6 + j];  // N = Wx^T in row-vector convention
    for (int it = 0; it < 5; ++it) {
        float P[6][6];
#pragma unroll
        for (int i = 0; i < 6; ++i)
#pragma unroll
            for (int j = 0; j < 6; ++j) {
                float a = 0.0f;
#pragma unroll
                for (int k = 0; k < 6; ++k) a = fmaf(M[i][k], M[k][j], a);
                P[i][j] = a;
            }
#pragma unroll
        for (int i = 0; i < 6; ++i)
#pragma unroll
            for (int j = 0; j < 6; ++j) M[i][j] = P[i][j];
    }
    float db[6] = {0.f, 0.f, 0.f, 0.f, 0.f, 0.f};
    for (int c = 0; c < CC; ++c) {
        float vv[6];
#pragma unroll
        for (int i = 0; i < 6; ++i) {
            const size_t idx = ((size_t)c * 6 + i) * BB + b;
            vv[i] = v[idx];
            v[idx] = db[i];  // overwrite with the start state for chunk c
        }
        float nd[6];
#pragma unroll
        for (int i = 0; i < 6; ++i) {
            float a = vv[i];
#pragma unroll
            for (int j = 0; j < 6; ++j) a = fmaf(db[j], M[j][i], a);
            nd[i] = a;
        }
#pragma unroll
        for (int i = 0; i < 6; ++i) db[i] = nd[i];
    }
}

// ---------------------------------------------------------------------------
// Phase 2.5: expand the recurrence to EVERY step and store db(t) packed fp16:
// dbh[t][k][b] (k=0..2, each uint = cvt_pkrtz(db[2k],db[2k+1])).
// Tiny register footprint; memory-bound (~280 MB traffic).
__global__ __launch_bounds__(256) void k_expand(
    const float* __restrict__ targets,
    const float* __restrict__ Wxg,
    const float* __restrict__ Wug,
    const float* __restrict__ dbs,
    uint32_t* __restrict__ dbh)
{
    const int b = blockIdx.x * 256 + threadIdx.x;
    const int c = blockIdx.y;
    float wx[6][6], wu[6];
#pragma unroll
    for (int i = 0; i < 6; ++i) {
        wu[i] = Wug[i];
#pragma unroll
        for (int j = 0; j < 6; ++j) wx[i][j] = Wxg[i * 6 + j];
    }
    float db[6];
#pragma unroll
    for (int i = 0; i < 6; ++i) db[i] = dbs[((size_t)c * 6 + i) * BB + b];

    const int t0 = c * LC;
#pragma unroll 4
    for (int s = 0; s < LC; ++s) {
        const int t = t0 + s;
        float u = 0.0f;
        if (t > 0) u = targets[(size_t)(t - 1) * BB + b];
        float nd[6];
#pragma unroll
        for (int i = 0; i < 6; ++i) {
            float a = u * wu[i];
#pragma unroll
            for (int j = 0; j < 6; ++j) a = fmaf(db[j], wx[i][j], a);
            nd[i] = a;
        }
#pragma unroll
        for (int i = 0; i < 6; ++i) db[i] = nd[i];
#pragma unroll
        for (int k = 0; k < 3; ++k) {
            h2 p = __builtin_amdgcn_cvt_pkrtz(db[2 * k], db[2 * k + 1]);
            dbh[((size_t)t * 3 + k) * BB + b] = __builtin_bit_cast(uint32_t, p);
        }
    }
}

// ---------------------------------------------------------------------------
// Phase 3: STATELESS MLP — one thread = one (t,b), no loop, so the 280
// wave-uniform weights are one-shot s_loads (SMEM pipe) instead of loop-
// resident VGPR state. This removes the AGPR/copy bloat that capped v2-v4
// (VGPR_Count 52 vs ~110 live floats). ~50 VGPRs -> 8 waves/SIMD.
__global__ __launch_bounds__(256) void k_mlp(
    const float* __restrict__ inputs,
    const uint32_t* __restrict__ dbh,
    const float* __restrict__ W1g,
    const float* __restrict__ b1g,
    const float* __restrict__ W2g,
    const float* __restrict__ b2g,
    float* __restrict__ out)
{
    const int b = blockIdx.x * 256 + threadIdx.x;
    const int t = blockIdx.y;

    float ni[12];
#pragma unroll
    for (int k = 0; k < 3; ++k) {
        uint32_t u = dbh[((size_t)t * 3 + k) * BB + b];
        h2 p = __builtin_bit_cast(h2, u);
        ni[2 * k]     = (float)p.x;
        ni[2 * k + 1] = (float)p.y;
    }
    const float* xp = inputs + ((size_t)t * BB + b) * 6;
    float2 x0 = *(const float2*)(xp);
    float2 x1 = *(const float2*)(xp + 2);
    float2 x2 = *(const float2*)(xp + 4);
    ni[6] = x0.x; ni[7] = x0.y; ni[8] = x1.x;
    ni[9] = x1.y; ni[10] = x2.x; ni[11] = x2.y;

    float acc[20];
#pragma unroll
    for (int m = 0; m < 20; ++m) acc[m] = b1g[m];
#pragma unroll
    for (int j = 0; j < 12; ++j) {
        const float nij = ni[j];
#pragma unroll
        for (int m = 0; m < 20; ++m) acc[m] = fmaf(W1g[m * 12 + j], nij, acc[m]);
    }
    float o = b2g[0];
#pragma unroll
    for (int m = 0; m < 20; ++m) o = fmaf(W2g[m], fast_tanh(acc[m]), o);

    out[(size_t)t * BB + b] = o;
}

// ---------------------------------------------------------------------------
// Fallback phase 3 (v4): four lanes per (c,b) column, 5 hidden units per lane.
// Used only if the workspace is too small for the db round-trip.
__global__ __launch_bounds__(256, 3) void k_phase3(
    const float* __restrict__ inputs,
    const float* __restrict__ targets,
    const float* __restrict__ Wxg,
    const float* __restrict__ Wug,
    const float* __restrict__ W1g,
    const float* __restrict__ b1g,
    const float* __restrict__ W2g,
    const float* __restrict__ b2g,
    const float* __restrict__ dbs,
    float* __restrict__ out)
{
    const int tid = threadIdx.x;
    const int q   = tid & 3;
    const int b   = blockIdx.x * 64 + (tid >> 2);
    const int c   = blockIdx.y;
    const int m0  = q * 5;

    float wx[6][6], wu[6];
#pragma unroll
    for (int i = 0; i < 6; ++i) {
        wu[i] = Wug[i];
#pragma unroll
        for (int j = 0; j < 6; ++j) wx[i][j] = Wxg[i * 6 + j];
    }
    const float vb2 = b2g[0];

    float w1l[5][12];
    float b1l[5], w2l[5];
#pragma unroll
    for (int p = 0; p < 5; ++p) {
#pragma unroll
        for (int j = 0; j < 12; ++j) w1l[p][j] = W1g[(m0 + p) * 12 + j];
        b1l[p] = b1g[m0 + p];
        w2l[p] = W2g[m0 + p];
    }

    float db[6];
#pragma unroll
    for (int i = 0; i < 6; ++i) db[i] = dbs[((size_t)c * 6 + i) * BB + b];

    const int t0 = c * LC;
    const float* xptr = inputs + ((size_t)t0 * BB + b) * 6;
    const float* tptr = targets + (size_t)t0 * BB + b;
    float* optr = out + (size_t)t0 * BB + b;

    float u_cur = (t0 == 0) ? 0.0f : tptr[-(ptrdiff_t)BB];
    float2 x0 = *(const float2*)(xptr);
    float2 x1 = *(const float2*)(xptr + 2);
    float2 x2 = *(const float2*)(xptr + 4);

    for (int s = 0; s < LC; ++s) {
        float u_nxt = 0.0f;
        float2 n0 = x0, n1 = x1, n2 = x2;
        if (s + 1 < LC) {
            u_nxt = *tptr;
            const float* xn = xptr + (size_t)BB * 6;
            n0 = *(const float2*)(xn);
            n1 = *(const float2*)(xn + 2);
            n2 = *(const float2*)(xn + 4);
        }
        float nd[6];
#pragma unroll
        for (int i = 0; i < 6; ++i) {
            float a = u_cur * wu[i];
#pragma unroll
            for (int j = 0; j < 6; ++j) a = fmaf(db[j], wx[i][j], a);
            nd[i] = a;
        }
#pragma unroll
        for (int i = 0; i < 6; ++i) db[i] = nd[i];

        const float ni[12] = {db[0], db[1], db[2], db[3], db[4], db[5],
                              x0.x, x0.y, x1.x, x1.y, x2.x, x2.y};
        float acc[5];
#pragma unroll
        for (int p = 0; p < 5; ++p) acc[p] = b1l[p];
#pragma unroll
        for (int j = 0; j < 12; ++j) {
            const float nij = ni[j];
#pragma unroll
            for (int p = 0; p < 5; ++p) acc[p] = fmaf(w1l[p][j], nij, acc[p]);
        }
        float o = 0.0f;
#pragma unroll
        for (int p = 0; p < 5; ++p) o = fmaf(w2l[p], fast_tanh(acc[p]), o);
        o += __shfl_xor(o, 1, 64);
        o += __shfl_xor(o, 2, 64);
        if (q == 0) *optr = o + vb2;

        u_cur = u_nxt; x0 = n0; x1 = n1; x2 = n2;
        xptr += (size_t)BB * 6;
        tptr += BB;
        optr += BB;
    }
}

extern "C" void kernel_launch(void* const* d_in, const int* in_sizes, int n_in,
                              void* d_out, int out_size, void* d_ws, size_t ws_size,
                              hipStream_t stream) {
    (void)in_sizes; (void)n_in; (void)out_size;
    const float* inputs  = (const float*)d_in[0];
    const float* targets = (const float*)d_in[1];
    const float* Wx = (const float*)d_in[2];
    const float* Wu = (const float*)d_in[3];
    const float* W1 = (const float*)d_in[4];
    const float* b1 = (const float*)d_in[5];
    const float* W2 = (const float*)d_in[6];
    const float* b2 = (const float*)d_in[7];
    float* out = (float*)d_out;

    float* v = (float*)d_ws;                       // CC*6*BB*4 = 12.6 MB
    const size_t v_elems   = (size_t)CC * 6 * BB;
    const size_t dbh_elems = (size_t)TT * 3 * BB;  // 201.3 MB as uint32
    const size_t need      = (v_elems + dbh_elems) * 4;

    dim3 blk(256);
    dim3 g1(BB / 256, CC);
    hipLaunchKernelGGL(k_phase1, g1, blk, 0, stream, targets, Wx, Wu, v);
    hipLaunchKernelGGL(k_phase2, dim3(BB / 256), blk, 0, stream, Wx, v);

    if (ws_size >= need) {
        uint32_t* dbh = (uint32_t*)(v + v_elems);
        hipLaunchKernelGGL(k_expand, g1, blk, 0, stream, targets, Wx, Wu, v, dbh);
        dim3 g3(BB / 256, TT);
        hipLaunchKernelGGL(k_mlp, g3, blk, 0, stream,
                           inputs, dbh, W1, b1, W2, b2, out);
    } else {
        dim3 g3(BB / 64, CC);
        hipLaunchKernelGGL(k_phase3, g3, blk, 0, stream,
                           inputs, targets, Wx, Wu, W1, b1, W2, b2, v, out);
    }
}

// Round 6
// 671.766 us; speedup vs baseline: 1.2179x; 1.0855x over previous
//
#include <hip/hip_runtime.h>
#include <cstddef>
#include <cstdint>

#define TT 1024
#define BB 16384
#define LC 32
#define CC (TT / LC)

// Exact tanh via the hardware exp2: tanh(x) = 1 - 2/(2^(2*log2e*x) + 1).
__device__ __forceinline__ float fast_tanh(float x) {
    float e = __builtin_amdgcn_exp2f(x * 2.8853900817779268f);   // 2*log2(e)
    return fmaf(-2.0f, __builtin_amdgcn_rcpf(e + 1.0f), 1.0f);
}

// ---------------------------------------------------------------------------
// Phase 1: per (chunk c, batch b) run the affine recurrence from zero state,
// store the chunk offset v[c][i][b]  (layout [C][6][B] for coalescing).
__global__ __launch_bounds__(256) void k_phase1(
    const float* __restrict__ targets,
    const float* __restrict__ Wx,
    const float* __restrict__ Wu,
    float* __restrict__ v)
{
    const int b = blockIdx.x * 256 + threadIdx.x;
    const int c = blockIdx.y;
    float wx[6][6], wu[6];
#pragma unroll
    for (int i = 0; i < 6; ++i) {
        wu[i] = Wu[i];
#pragma unroll
        for (int j = 0; j < 6; ++j) wx[i][j] = Wx[i * 6 + j];
    }
    float db[6] = {0.f, 0.f, 0.f, 0.f, 0.f, 0.f};
    const int t0 = c * LC;
#pragma unroll 4
    for (int s = 0; s < LC; ++s) {
        const int t = t0 + s;
        float u = 0.0f;
        if (t > 0) u = targets[(size_t)(t - 1) * BB + b];
        float nd[6];
#pragma unroll
        for (int i = 0; i < 6; ++i) {
            float a = u * wu[i];
#pragma unroll
            for (int j = 0; j < 6; ++j) a = fmaf(db[j], wx[i][j], a);
            nd[i] = a;
        }
#pragma unroll
        for (int i = 0; i < 6; ++i) db[i] = nd[i];
    }
#pragma unroll
    for (int i = 0; i < 6; ++i) v[((size_t)c * 6 + i) * BB + b] = db[i];
}

// ---------------------------------------------------------------------------
// Phase 2: per batch b, sequential prefix over the 32 chunks.
// db_start[c+1] = db_start[c] * M + v[c],  M = (Wx^T)^32 (5 squarings).
// In-place: v[c][.][b] is replaced by db_start[c][.][b].
__global__ __launch_bounds__(256) void k_phase2(
    const float* __restrict__ Wx,
    float* __restrict__ v)
{
    const int b = blockIdx.x * 256 + threadIdx.x;
    float M[6][6];
#pragma unroll
    for (int i = 0; i < 6; ++i)
#pragma unroll
        for (int j = 0; j < 6; ++j)
            M[j][i] = Wx[i * 6 + j];  // N = Wx^T in row-vector convention
    for (int it = 0; it < 5; ++it) {
        float P[6][6];
#pragma unroll
        for (int i = 0; i < 6; ++i)
#pragma unroll
            for (int j = 0; j < 6; ++j) {
                float a = 0.0f;
#pragma unroll
                for (int k = 0; k < 6; ++k) a = fmaf(M[i][k], M[k][j], a);
                P[i][j] = a;
            }
#pragma unroll
        for (int i = 0; i < 6; ++i)
#pragma unroll
            for (int j = 0; j < 6; ++j) M[i][j] = P[i][j];
    }
    float db[6] = {0.f, 0.f, 0.f, 0.f, 0.f, 0.f};
    for (int c = 0; c < CC; ++c) {
        float vv[6];
#pragma unroll
        for (int i = 0; i < 6; ++i) {
            const size_t idx = ((size_t)c * 6 + i) * BB + b;
            vv[i] = v[idx];
            v[idx] = db[i];  // overwrite with the start state for chunk c
        }
        float nd[6];
#pragma unroll
        for (int i = 0; i < 6; ++i) {
            float a = vv[i];
#pragma unroll
            for (int j = 0; j < 6; ++j) a = fmaf(db[j], M[j][i], a);
            nd[i] = a;
        }
#pragma unroll
        for (int i = 0; i < 6; ++i) db[i] = nd[i];
    }
}

// ---------------------------------------------------------------------------
// Phase 3 (fused v6.1): one thread = one (chunk c, column b). db recurrence
// in 6 registers (fp32, no quantization, no duplication, no shuffles); the
// 281 MLP weights live in LDS (1.1 KB/block) and are re-read EVERY STEP as
// uniform-address ds_read broadcasts (conflict-free; LDS pipe overlaps the
// VALU stream; one-FMA live ranges -> no register pressure). The per-step
// asm "memory" barrier + unroll-1 make it ILLEGAL for the compiler to hoist
// the weight reads out of the loop — the v2-v4 failure mode.
// ROUND-5 BUG FIX: LDS staging predicates now fit in 256 threads (the old
// `else if (tid < 280)` branches needed threads 256-279, which don't exist —
// w2s/b1s[16..19] were uninitialized garbage).
__global__ __launch_bounds__(256) void k_fused(
    const float* __restrict__ inputs,
    const float* __restrict__ targets,
    const float* __restrict__ Wxg,
    const float* __restrict__ Wug,
    const float* __restrict__ W1g,
    const float* __restrict__ b1g,
    const float* __restrict__ W2g,
    const float* __restrict__ b2g,
    const float* __restrict__ dbs,
    float* __restrict__ out)
{
    __shared__ float w1s[20][12];   // 48 B rows, 16 B aligned
    __shared__ float b1s[20];
    __shared__ float w2s[20];

    const int tid = threadIdx.x;
    if (tid < 240) w1s[tid / 12][tid % 12] = W1g[tid];
    if (tid < 20) {                 // overlapping predicate, fits 256 threads
        b1s[tid] = b1g[tid];
        w2s[tid] = W2g[tid];
    }

    // Wave-uniform recurrence weights -> SGPRs (small enough to hoist).
    float wx[6][6], wu[6];
#pragma unroll
    for (int i = 0; i < 6; ++i) {
        wu[i] = Wug[i];
#pragma unroll
        for (int j = 0; j < 6; ++j) wx[i][j] = Wxg[i * 6 + j];
    }
    const float vb2 = b2g[0];

    const int b = blockIdx.x * 256 + tid;
    const int c = blockIdx.y;

    float db[6];
#pragma unroll
    for (int i = 0; i < 6; ++i) db[i] = dbs[((size_t)c * 6 + i) * BB + b];

    __syncthreads();

    const int t0 = c * LC;
    const float* xptr = inputs + ((size_t)t0 * BB + b) * 6;
    const float* tptr = targets + (size_t)t0 * BB + b;   // = u for step t0+1
    float* optr = out + (size_t)t0 * BB + b;

    float u_cur = (t0 == 0) ? 0.0f : tptr[-(ptrdiff_t)BB];
    float2 x0 = *(const float2*)(xptr);
    float2 x1 = *(const float2*)(xptr + 2);
    float2 x2 = *(const float2*)(xptr + 4);

#pragma unroll 1
    for (int s = 0; s < LC; ++s) {
        // Issue next step's loads early (addresses recurrence-independent).
        float u_nxt = 0.0f;
        float2 n0 = x0, n1 = x1, n2 = x2;
        if (s + 1 < LC) {
            u_nxt = *tptr;
            const float* xn = xptr + (size_t)BB * 6;
            n0 = *(const float2*)(xn);
            n1 = *(const float2*)(xn + 2);
            n2 = *(const float2*)(xn + 4);
        }

        // Compile-time memory barrier: weight ds_reads below cannot be
        // hoisted out of the loop into registers.
        asm volatile("" ::: "memory");

        // Delay-buffer update (42 FMAs; wx/wu from SGPRs).
        float nd[6];
#pragma unroll
        for (int i = 0; i < 6; ++i) {
            float a = u_cur * wu[i];
#pragma unroll
            for (int j = 0; j < 6; ++j) a = fmaf(db[j], wx[i][j], a);
            nd[i] = a;
        }
#pragma unroll
        for (int i = 0; i < 6; ++i) db[i] = nd[i];

        const float ni[12] = {db[0], db[1], db[2], db[3], db[4], db[5],
                              x0.x, x0.y, x1.x, x1.y, x2.x, x2.y};

        // MLP: all 20 units per thread, weights streamed from LDS as
        // uniform-address ds_read_b128 broadcasts (3 per unit).
        float o = 0.0f;
#pragma unroll
        for (int m = 0; m < 20; ++m) {
            const float4 wa = *(const float4*)(&w1s[m][0]);
            const float4 wb = *(const float4*)(&w1s[m][4]);
            const float4 wc = *(const float4*)(&w1s[m][8]);
            float a = b1s[m];
            a = fmaf(wa.x, ni[0], a);  a = fmaf(wa.y, ni[1], a);
            a = fmaf(wa.z, ni[2], a);  a = fmaf(wa.w, ni[3], a);
            a = fmaf(wb.x, ni[4], a);  a = fmaf(wb.y, ni[5], a);
            a = fmaf(wb.z, ni[6], a);  a = fmaf(wb.w, ni[7], a);
            a = fmaf(wc.x, ni[8], a);  a = fmaf(wc.y, ni[9], a);
            a = fmaf(wc.z, ni[10], a); a = fmaf(wc.w, ni[11], a);
            o = fmaf(w2s[m], fast_tanh(a), o);
        }
        *optr = o + vb2;

        u_cur = u_nxt; x0 = n0; x1 = n1; x2 = n2;
        xptr += (size_t)BB * 6;
        tptr += BB;
        optr += BB;
    }
}

extern "C" void kernel_launch(void* const* d_in, const int* in_sizes, int n_in,
                              void* d_out, int out_size, void* d_ws, size_t ws_size,
                              hipStream_t stream) {
    (void)in_sizes; (void)n_in; (void)out_size; (void)ws_size;
    const float* inputs  = (const float*)d_in[0];
    const float* targets = (const float*)d_in[1];
    const float* Wx = (const float*)d_in[2];
    const float* Wu = (const float*)d_in[3];
    const float* W1 = (const float*)d_in[4];
    const float* b1 = (const float*)d_in[5];
    const float* W2 = (const float*)d_in[6];
    const float* b2 = (const float*)d_in[7];
    float* out = (float*)d_out;
    float* v   = (float*)d_ws;  // needs CC*6*BB*4 = 12.6 MB of workspace

    dim3 blk(256);
    dim3 g1(BB / 256, CC);
    hipLaunchKernelGGL(k_phase1, g1, blk, 0, stream, targets, Wx, Wu, v);
    hipLaunchKernelGGL(k_phase2, dim3(BB / 256), blk, 0, stream, Wx, v);
    hipLaunchKernelGGL(k_fused, g1, blk, 0, stream,
                       inputs, targets, Wx, Wu, W1, b1, W2, b2, v, out);
}